// Round 16
// baseline (206.596 us; speedup 1.0000x reference)
//
#include <hip/hip_runtime.h>
#include <hip/hip_bf16.h>

#define BB 8
#define SS 1024
#define DM 512
#define HH 8
#define BM 128
#define BN 128
#define BK 32
#define LD 40   // LDS row stride (bf16 elems): 80 B = 16B-aligned, 2-way banks

typedef __bf16 bf16x8 __attribute__((ext_vector_type(8)));
typedef __bf16 bf16x4 __attribute__((ext_vector_type(4)));
typedef float f32x4 __attribute__((ext_vector_type(4)));

__device__ __forceinline__ f32x4 mfma16(bf16x8 a, bf16x8 b, f32x4 c) {
    return __builtin_amdgcn_mfma_f32_16x16x32_bf16(a, b, c, 0, 0, 0);
}

// ---------------- W transpose + hi/lo split ----------------
__global__ __launch_bounds__(256) void wconv(
    const float* __restrict__ W0, const float* __restrict__ W1,
    const float* __restrict__ W2, const float* __restrict__ W3,
    __bf16* __restrict__ th, __bf16* __restrict__ tl)
{
    const float* W = blockIdx.z == 0 ? W0 : blockIdx.z == 1 ? W1
                   : blockIdx.z == 2 ? W2 : W3;
    __bf16* oh = th + (size_t)blockIdx.z * 512 * 512;
    __bf16* ol = tl + (size_t)blockIdx.z * 512 * 512;
    __shared__ float T[64][65];
    const int k0 = blockIdx.x * 64, n0 = blockIdx.y * 64;
    const int r = threadIdx.x >> 4, c4 = (threadIdx.x & 15) * 4;
    #pragma unroll
    for (int p = 0; p < 4; ++p) {
        float4 v = *(const float4*)(W + (size_t)(k0 + p * 16 + r) * 512 + n0 + c4);
        T[p * 16 + r][c4 + 0] = v.x; T[p * 16 + r][c4 + 1] = v.y;
        T[p * 16 + r][c4 + 2] = v.z; T[p * 16 + r][c4 + 3] = v.w;
    }
    __syncthreads();
    #pragma unroll
    for (int p = 0; p < 4; ++p) {
        int n = n0 + p * 16 + r;
        bf16x4 h4, l4;
        #pragma unroll
        for (int j = 0; j < 4; ++j) {
            float x = T[c4 + j][p * 16 + r];
            __bf16 h = (__bf16)x;
            h4[j] = h; l4[j] = (__bf16)(x - (float)h);
        }
        *(bf16x4*)(oh + (size_t)n * 512 + k0 + c4) = h4;
        *(bf16x4*)(ol + (size_t)n * 512 + k0 + c4) = l4;
    }
}

// ---------------- LDS-staged tile GEMM ----------------
template<int MODE>
__global__ __launch_bounds__(256, 3) void gemm_tile(
    const float* __restrict__ Aq, const float* __restrict__ Ak,
    const float* __restrict__ Av,
    const __bf16* __restrict__ Ahig, const __bf16* __restrict__ Alog,
    const __bf16* __restrict__ Wth, const __bf16* __restrict__ Wtl,
    const float* __restrict__ bq, const float* __restrict__ bk,
    const float* __restrict__ bv,
    float* __restrict__ Cf, __bf16* __restrict__ qo, __bf16* __restrict__ ko,
    __bf16* __restrict__ vo)
{
    __shared__ __align__(16) __bf16 Ah[BM][LD];
    __shared__ __align__(16) __bf16 Al[(MODE == 1 ? BM : 1)][LD];
    __shared__ __align__(16) __bf16 Bh[BN][LD];
    __shared__ __align__(16) __bf16 Bl[BN][LD];

    const int tid = threadIdx.x;
    const int w = tid >> 6, lane = tid & 63, l15 = lane & 15, lg = lane >> 4;
    const int wm = w >> 1, wn = w & 1;
    const int bx = blockIdx.x;
    const int z  = MODE == 0 ? (bx >> 2) : 3;
    const int n0 = MODE == 0 ? (bx & 3) * BN : bx * BN;
    const int m0 = blockIdx.y * BM;

    const float* Afp = (MODE == 0) ? (z == 0 ? Aq : z == 1 ? Ak : Av) : nullptr;
    const __bf16* wh = Wth + (size_t)z * 512 * 512;
    const __bf16* wl = Wtl + (size_t)z * 512 * 512;

    f32x4 acc[4][4];
    #pragma unroll
    for (int i = 0; i < 4; ++i)
        #pragma unroll
        for (int j = 0; j < 4; ++j) acc[i][j] = (f32x4){0.f, 0.f, 0.f, 0.f};

    for (int k0 = 0; k0 < 512; k0 += BK) {
        __syncthreads();
        if (MODE == 0) {
            const int row = tid >> 3, c = (tid & 7) * 4;
            #pragma unroll
            for (int p = 0; p < 4; ++p) {
                int rr = row + p * 32;
                f32x4 a = *(const f32x4*)(Afp + (size_t)(m0 + rr) * 512 + k0 + c);
                bf16x4 h4;
                #pragma unroll
                for (int j = 0; j < 4; ++j) h4[j] = (__bf16)a[j];
                *(bf16x4*)&Ah[rr][c] = h4;
            }
        } else {
            const int row = tid >> 2, c = (tid & 3) * 8;
            #pragma unroll
            for (int p = 0; p < 2; ++p) {
                int rr = row + p * 64;
                *(bf16x8*)&Ah[rr][c] =
                    *(const bf16x8*)(Ahig + (size_t)(m0 + rr) * 512 + k0 + c);
                *(bf16x8*)&Al[rr][c] =
                    *(const bf16x8*)(Alog + (size_t)(m0 + rr) * 512 + k0 + c);
            }
        }
        {
            const int row = tid >> 2, c = (tid & 3) * 8;
            #pragma unroll
            for (int p = 0; p < 2; ++p) {
                int rr = row + p * 64;
                *(bf16x8*)&Bh[rr][c] =
                    *(const bf16x8*)(wh + (size_t)(n0 + rr) * 512 + k0 + c);
                *(bf16x8*)&Bl[rr][c] =
                    *(const bf16x8*)(wl + (size_t)(n0 + rr) * 512 + k0 + c);
            }
        }
        __syncthreads();

        bf16x8 afh[4], afl[4];
        #pragma unroll
        for (int mt = 0; mt < 4; ++mt) {
            afh[mt] = *(const bf16x8*)&Ah[wm * 64 + mt * 16 + l15][lg * 8];
            if (MODE == 1)
                afl[mt] = *(const bf16x8*)&Al[wm * 64 + mt * 16 + l15][lg * 8];
        }
        #pragma unroll
        for (int nt = 0; nt < 4; ++nt) {
            bf16x8 bfh = *(const bf16x8*)&Bh[wn * 64 + nt * 16 + l15][lg * 8];
            bf16x8 bfl = *(const bf16x8*)&Bl[wn * 64 + nt * 16 + l15][lg * 8];
            #pragma unroll
            for (int mt = 0; mt < 4; ++mt) {
                acc[mt][nt] = mfma16(afh[mt], bfh, acc[mt][nt]);
                acc[mt][nt] = mfma16(afh[mt], bfl, acc[mt][nt]);
                if (MODE == 1)
                    acc[mt][nt] = mfma16(afl[mt], bfh, acc[mt][nt]);
            }
        }
    }

    const float* bias = (MODE == 1) ? bq : (z == 0 ? bq : z == 1 ? bk : bv);
    #pragma unroll
    for (int nt = 0; nt < 4; ++nt) {
        const int n = n0 + wn * 64 + nt * 16 + l15;
        const float bz = bias[n];
        #pragma unroll
        for (int mt = 0; mt < 4; ++mt) {
            if (MODE == 0 && z == 2) {
                bf16x4 v4;
                int mbase = m0 + wm * 64 + mt * 16 + lg * 4;
                #pragma unroll
                for (int rr = 0; rr < 4; ++rr)
                    v4[rr] = (__bf16)(acc[mt][nt][rr] + bz);
                int bb = mbase >> 10, s = mbase & 1023, h = n >> 6, d = n & 63;
                *(bf16x4*)(vo + ((size_t)(bb * HH + h) * 64 + d) * SS + s) = v4;
            } else {
                #pragma unroll
                for (int rr = 0; rr < 4; ++rr) {
                    int m = m0 + wm * 64 + mt * 16 + lg * 4 + rr;
                    float v = acc[mt][nt][rr] + bz;
                    if (MODE == 1) {
                        Cf[(size_t)m * 512 + n] = v;
                    } else {
                        int bb = m >> 10, s = m & 1023, h = n >> 6, d = n & 63;
                        __bf16* outp = z == 0 ? qo : ko;
                        outp[((size_t)(bb * HH + h) * SS + s) * 64 + d] = (__bf16)v;
                    }
                }
            }
        }
    }
}

// ---------------- G precompute ----------------
__global__ __launch_bounds__(256) void gprep(
    const float* __restrict__ mask, const float* __restrict__ adj,
    const float* __restrict__ dist,
    __bf16* __restrict__ Gg, float* __restrict__ rowILg)
{
    const int w = threadIdx.x >> 6, lane = threadIdx.x & 63;
    const int row = blockIdx.x * 4 + w;
    const int b = row >> 10;
    const size_t drow = (size_t)row * SS;
    const float L2E = 1.44269504f;
    const float* mrow = mask + (size_t)b * SS;
    float sm = 0.f;
    #pragma unroll
    for (int j = 0; j < 4; ++j) {
        int c = lane * 4 + j * 256;
        f32x4 d4 = *(const f32x4*)(dist + drow + c);
        f32x4 a4 = *(const f32x4*)(adj + drow + c);
        f32x4 m4 = *(const f32x4*)(mrow + c);
        bf16x4 g4;
        #pragma unroll
        for (int r = 0; r < 4; ++r) {
            float e = exp2f(fmaf(m4[r], -1e9f * L2E, fmaf(d4[r], L2E, -L2E)));
            sm += e;
            g4[r] = (__bf16)(a4[r] * e);
        }
        *(bf16x4*)(Gg + drow + c) = g4;
    }
    #pragma unroll
    for (int off = 1; off <= 32; off <<= 1)
        sm += __shfl_xor(sm, off, 64);
    if (lane == 0) rowILg[row] = 1.0f / sm;
}

// ---------------- Fused attention v11: 64 q-rows/block, dbuf KV, T14 pipeline ----------------
// grid 1024: h = bid&7, b = (bid>>3)&7, q0 = (bid>>6)*64. 1024 thr = 16 waves.
// K,V staged ONCE per 64 q-rows (half the fabric traffic of v10). One barrier
// per chunk via double-buffered KV. P[64][1024] bf16 in LDS (swizzled).
__global__ __launch_bounds__(1024, 4) void attn11(
    const __bf16* __restrict__ qh_, const __bf16* __restrict__ kh,
    const __bf16* __restrict__ vt,
    const float* __restrict__ mask, const __bf16* __restrict__ Gg,
    const float* __restrict__ rowILg,
    float* __restrict__ attn_out, __bf16* __restrict__ chi, __bf16* __restrict__ clo)
{
    __shared__ float nmb[1024];                        // 4 KB
    __shared__ __align__(16) __bf16 P[64][1024];       // 128 KB, swizzled
    __shared__ __align__(16) __bf16 KV[2][64][64];     // 2 x 8 KB dbuf, swizzled
    __shared__ float redl[16][16];

    const int tid = threadIdx.x;
    const int w = tid >> 6, lane = tid & 63, l15 = lane & 15, lg = lane >> 4;
    const int bid = blockIdx.x;
    const int h = bid & 7;
    const int b = (bid >> 3) & 7;
    const int q0 = (bid >> 6) * 64;
    const float L2E = 1.44269504f;
    const float c1 = 0.125f * L2E;

    char* Pb = (char*)P;
    char* KVb = (char*)KV;
    const int srow = tid >> 4;               // staging row (64 rows, 16 thr/row)
    const int scol = (tid & 15) * 4;         // staging elem offset within row
    const int sdst = srow * 128 + ((scol * 2) ^ ((srow & 7) << 4));

    nmb[tid] = fmaf(mask[(size_t)b * SS + tid], -1e9f * L2E, -16.0f * L2E);

    const size_t hb = ((size_t)(b * HH + h)) * SS * 64;
    const int qsub = w >> 2, ktw = w & 3;    // pass1 role
    bf16x8 qf0 = *(const bf16x8*)(qh_ + hb + (size_t)(q0 + qsub * 16 + l15) * 64 + lg * 8);
    bf16x8 qf1 = *(const bf16x8*)(qh_ + hb + (size_t)(q0 + qsub * 16 + l15) * 64 + 32 + lg * 8);

    const int krow = ktw * 16 + l15;
    const int kswz = (krow & 7) << 4;
    const int prow = qsub * 16 + l15;
    const int pswz = (prow & 7) << 4;

    // ---- pass 1: 16 chunks of 64 keys, dbuf + reg pipeline ----
    const __bf16* kcp = kh + hb + (size_t)srow * 64 + scol;
    bf16x4 kvreg = *(const bf16x4*)kcp;                    // chunk 0
    *(bf16x4*)(KVb + sdst) = kvreg;                        // buf 0
    __syncthreads();
    float lac = 0.f;
    for (int c = 0; c < 16; ++c) {
        if (c + 1 < 16)
            kvreg = *(const bf16x4*)(kcp + (size_t)(c + 1) * 4096);
        const char* kb = KVb + (c & 1) * 8192;
        bf16x8 k0v = *(const bf16x8*)(kb + krow * 128 + ((lg * 16) ^ kswz));
        bf16x8 k1v = *(const bf16x8*)(kb + krow * 128 + ((64 + lg * 16) ^ kswz));
        f32x4 acc = {0.f, 0.f, 0.f, 0.f};
        acc = mfma16(k0v, qf0, acc);
        acc = mfma16(k1v, qf1, acc);
        const int key4 = c * 64 + ktw * 16 + lg * 4;
        f32x4 nb4 = *(const f32x4*)&nmb[key4];
        float e0 = exp2f(fmaf(acc[0], c1, nb4[0]));
        float e1 = exp2f(fmaf(acc[1], c1, nb4[1]));
        float e2 = exp2f(fmaf(acc[2], c1, nb4[2]));
        float e3 = exp2f(fmaf(acc[3], c1, nb4[3]));
        lac += (e0 + e1) + (e2 + e3);
        bf16x4 pb;
        pb[0] = (__bf16)e0; pb[1] = (__bf16)e1;
        pb[2] = (__bf16)e2; pb[3] = (__bf16)e3;
        *(bf16x4*)(Pb + prow * 2048 + ((key4 * 2) ^ pswz)) = pb;
        if (c + 1 < 16)
            *(bf16x4*)(KVb + ((c + 1) & 1) * 8192 + sdst) = kvreg;
        __syncthreads();
    }
    #pragma unroll
    for (int off = 16; off <= 32; off <<= 1)
        lac += __shfl_xor(lac, off, 64);
    if (lg == 0) redl[w][l15] = lac;
    __syncthreads();

    // ---- gate phase: wave w -> q-rows [4w, 4w+4); G coalesced; fold coef ----
    const float* rg = rowILg + (size_t)b * SS + q0;
    float* aoutb = attn_out + ((size_t)(b * HH + h)) * SS * SS;
    const __bf16* gb = Gg + ((size_t)b * SS + q0) * SS;
    #pragma unroll
    for (int r = 0; r < 4; ++r) {
        const int row = w * 4 + r;
        const int rs = (row >> 4) * 4;
        const float ltot = redl[rs][row & 15] + redl[rs + 1][row & 15]
                         + redl[rs + 2][row & 15] + redl[rs + 3][row & 15];
        const float coefR = rg[row] / ltot;
        const int rswz = (row & 7) << 4;
        float* ar = aoutb + (size_t)(q0 + row) * SS;
        const __bf16* gr = gb + (size_t)row * SS;
        #pragma unroll
        for (int j = 0; j < 4; ++j) {
            const int off = lane * 8 + j * 512;            // bytes within P row
            char* pp = Pb + row * 2048 + (off ^ rswz);
            bf16x4 e4 = *(const bf16x4*)pp;
            bf16x4 g4 = *(const bf16x4*)(gr + (off >> 1));
            f32x4 av;
            bf16x4 pb;
            #pragma unroll
            for (int r2 = 0; r2 < 4; ++r2) {
                float v = (float)e4[r2] * (float)g4[r2] * coefR;
                av[r2] = v;
                pb[r2] = (__bf16)v;
            }
            __builtin_nontemporal_store(av, (f32x4*)(ar + (off >> 1)));
            *(bf16x4*)pp = pb;
        }
    }

    // ---- PV: 16 waves = 4q x 4d; V chunks dbuf + reg pipeline ----
    const int dh = w & 3;                    // reuse ktw slot as d-tile
    const int vrow = dh * 16 + l15;
    const int vswz = (vrow & 7) << 4;
    f32x4 cacc = {0.f, 0.f, 0.f, 0.f};
    const __bf16* vcp = vt + ((size_t)(b * HH + h) * 64 + srow) * SS + scol;
    bf16x4 vreg = *(const bf16x4*)vcp;                     // chunk 0
    *(bf16x4*)(KVb + sdst) = vreg;                         // buf 0 (gate writes done per-thread)
    __syncthreads();                                        // all gate writes + buf0 visible
    for (int c = 0; c < 16; ++c) {
        if (c + 1 < 16)
            vreg = *(const bf16x4*)(vcp + (c + 1) * 64);
        const char* vbuf = KVb + (c & 1) * 8192;
        #pragma unroll
        for (int ks = 0; ks < 2; ++ks) {
            bf16x8 pa = *(const bf16x8*)(Pb + prow * 2048
                          + ((c * 128 + ks * 64 + lg * 16) ^ pswz));
            bf16x8 vv = *(const bf16x8*)(vbuf + vrow * 128 + ((ks * 64 + lg * 16) ^ vswz));
            cacc = mfma16(pa, vv, cacc);
        }
        if (c + 1 < 16)
            *(bf16x4*)(KVb + ((c + 1) & 1) * 8192 + sdst) = vreg;
        __syncthreads();
    }

    // ---- epilogue: coef already folded; write ctx hi/lo ----
    #pragma unroll
    for (int r = 0; r < 4; ++r) {
        const int row = qsub * 16 + lg * 4 + r;
        float x = cacc[r];
        __bf16 hv = (__bf16)x;
        size_t idx = ((size_t)b * SS + q0 + row) * DM + h * 64 + dh * 16 + l15;
        chi[idx] = hv;
        clo[idx] = (__bf16)(x - (float)hv);
    }
}

extern "C" void kernel_launch(void* const* d_in, const int* in_sizes, int n_in,
                              void* d_out, int out_size, void* d_ws, size_t ws_size,
                              hipStream_t stream) {
    const float* q    = (const float*)d_in[0];
    const float* k    = (const float*)d_in[1];
    const float* v    = (const float*)d_in[2];
    const float* mask = (const float*)d_in[3];
    const float* adj  = (const float*)d_in[4];
    const float* dist = (const float*)d_in[5];
    const float* Wq   = (const float*)d_in[6];
    const float* bq   = (const float*)d_in[7];
    const float* Wk   = (const float*)d_in[8];
    const float* bk   = (const float*)d_in[9];
    const float* Wv   = (const float*)d_in[10];
    const float* bv   = (const float*)d_in[11];
    const float* Wo   = (const float*)d_in[12];
    const float* bo   = (const float*)d_in[13];

    const size_t NT = (size_t)BB * SS * DM;   // 4,194,304
    const size_t WN = 512 * 512;
    const size_t NSS = (size_t)BB * SS * SS;  // 8,388,608
    __bf16* wth = (__bf16*)d_ws;
    __bf16* wtl = wth + 4 * WN;
    __bf16* qhb = wtl + 4 * WN;
    __bf16* khb = qhb + NT;
    __bf16* vtb = khb + NT;
    __bf16* chi = vtb + NT;
    __bf16* clo = chi + NT;
    __bf16* Gg  = clo + NT;
    float* rowILg = (float*)(Gg + NSS);

    float* outp = (float*)d_out;
    float* attn = outp + NT;

    wconv<<<dim3(8, 8, 4), 256, 0, stream>>>(Wq, Wk, Wv, Wo, wth, wtl);

    gprep<<<2048, 256, 0, stream>>>(mask, adj, dist, Gg, rowILg);

    gemm_tile<0><<<dim3(12, 64), 256, 0, stream>>>(
        q, k, v, nullptr, nullptr, wth, wtl, bq, bk, bv,
        nullptr, qhb, khb, vtb);

    attn11<<<1024, 1024, 0, stream>>>(qhb, khb, vtb, mask, Gg, rowILg, attn, chi, clo);

    gemm_tile<1><<<dim3(4, 64), 256, 0, stream>>>(
        nullptr, nullptr, nullptr, chi, clo, wth, wtl, bo, nullptr, nullptr,
        outp, nullptr, nullptr, nullptr);
}

// Round 17
// 194.344 us; speedup vs baseline: 1.0630x; 1.0630x over previous
//
#include <hip/hip_runtime.h>
#include <hip/hip_bf16.h>

#define BB 8
#define SS 1024
#define DM 512
#define HH 8
#define BM 128
#define BN 128
#define BK 32
#define LD 40   // LDS row stride (bf16 elems): 80 B = 16B-aligned, 2-way banks

typedef __bf16 bf16x8 __attribute__((ext_vector_type(8)));
typedef __bf16 bf16x4 __attribute__((ext_vector_type(4)));
typedef float f32x4 __attribute__((ext_vector_type(4)));

__device__ __forceinline__ f32x4 mfma16(bf16x8 a, bf16x8 b, f32x4 c) {
    return __builtin_amdgcn_mfma_f32_16x16x32_bf16(a, b, c, 0, 0, 0);
}

// ---------------- W transpose + hi/lo split ----------------
__global__ __launch_bounds__(256) void wconv(
    const float* __restrict__ W0, const float* __restrict__ W1,
    const float* __restrict__ W2, const float* __restrict__ W3,
    __bf16* __restrict__ th, __bf16* __restrict__ tl)
{
    const float* W = blockIdx.z == 0 ? W0 : blockIdx.z == 1 ? W1
                   : blockIdx.z == 2 ? W2 : W3;
    __bf16* oh = th + (size_t)blockIdx.z * 512 * 512;
    __bf16* ol = tl + (size_t)blockIdx.z * 512 * 512;
    __shared__ float T[64][65];
    const int k0 = blockIdx.x * 64, n0 = blockIdx.y * 64;
    const int r = threadIdx.x >> 4, c4 = (threadIdx.x & 15) * 4;
    #pragma unroll
    for (int p = 0; p < 4; ++p) {
        float4 v = *(const float4*)(W + (size_t)(k0 + p * 16 + r) * 512 + n0 + c4);
        T[p * 16 + r][c4 + 0] = v.x; T[p * 16 + r][c4 + 1] = v.y;
        T[p * 16 + r][c4 + 2] = v.z; T[p * 16 + r][c4 + 3] = v.w;
    }
    __syncthreads();
    #pragma unroll
    for (int p = 0; p < 4; ++p) {
        int n = n0 + p * 16 + r;
        bf16x4 h4, l4;
        #pragma unroll
        for (int j = 0; j < 4; ++j) {
            float x = T[c4 + j][p * 16 + r];
            __bf16 h = (__bf16)x;
            h4[j] = h; l4[j] = (__bf16)(x - (float)h);
        }
        *(bf16x4*)(oh + (size_t)n * 512 + k0 + c4) = h4;
        *(bf16x4*)(ol + (size_t)n * 512 + k0 + c4) = l4;
    }
}

// ---------------- QKV projection GEMM, BN=256 (halved A re-reads) ----------------
// grid (6, 64): z = bx>>1, n0 = (bx&1)*256, m0 = by*128. 512 thr = 8 waves
// (wm = w>>2 in {0,1}, wn = w&3): wave tile 64m x 64n. A fp32 -> single bf16;
// W hi/lo (2 MFMA). LDS 50 KB -> 2 blocks/CU (16 waves).
__global__ __launch_bounds__(512, 4) void gemm_qkv2(
    const float* __restrict__ Aq, const float* __restrict__ Ak,
    const float* __restrict__ Av,
    const __bf16* __restrict__ Wth, const __bf16* __restrict__ Wtl,
    const float* __restrict__ bq, const float* __restrict__ bk,
    const float* __restrict__ bv,
    __bf16* __restrict__ qo, __bf16* __restrict__ ko, __bf16* __restrict__ vo)
{
    __shared__ __align__(16) __bf16 Ah[128][LD];
    __shared__ __align__(16) __bf16 Bh[256][LD];
    __shared__ __align__(16) __bf16 Bl[256][LD];

    const int tid = threadIdx.x;
    const int w = tid >> 6, lane = tid & 63, l15 = lane & 15, lg = lane >> 4;
    const int wm = w >> 2, wn = w & 3;
    const int bx = blockIdx.x;
    const int z  = bx >> 1;
    const int n0 = (bx & 1) * 256;
    const int m0 = blockIdx.y * 128;

    const float* Afp = z == 0 ? Aq : z == 1 ? Ak : Av;
    const __bf16* wh = Wth + (size_t)z * 512 * 512;
    const __bf16* wl = Wtl + (size_t)z * 512 * 512;

    f32x4 acc[4][4];
    #pragma unroll
    for (int i = 0; i < 4; ++i)
        #pragma unroll
        for (int j = 0; j < 4; ++j) acc[i][j] = (f32x4){0.f, 0.f, 0.f, 0.f};

    const int arow = tid >> 2, ac = (tid & 3) * 8;       // A stage: 4 thr/row
    const int wrow = tid >> 1, wc = (tid & 1) * 16;      // W stage: 2 thr/row

    for (int k0 = 0; k0 < 512; k0 += BK) {
        __syncthreads();
        {   // stage A: 128 x 32 fp32 -> bf16
            const float* ap = Afp + (size_t)(m0 + arow) * 512 + k0 + ac;
            f32x4 a0 = *(const f32x4*)ap;
            f32x4 a1 = *(const f32x4*)(ap + 4);
            bf16x8 h8;
            #pragma unroll
            for (int j = 0; j < 4; ++j) { h8[j] = (__bf16)a0[j]; h8[4 + j] = (__bf16)a1[j]; }
            *(bf16x8*)&Ah[arow][ac] = h8;
        }
        {   // stage W: 256 x 32, hi + lo
            const __bf16* wp = wh + (size_t)(n0 + wrow) * 512 + k0 + wc;
            const __bf16* lp = wl + (size_t)(n0 + wrow) * 512 + k0 + wc;
            *(bf16x8*)&Bh[wrow][wc]     = *(const bf16x8*)wp;
            *(bf16x8*)&Bh[wrow][wc + 8] = *(const bf16x8*)(wp + 8);
            *(bf16x8*)&Bl[wrow][wc]     = *(const bf16x8*)lp;
            *(bf16x8*)&Bl[wrow][wc + 8] = *(const bf16x8*)(lp + 8);
        }
        __syncthreads();

        bf16x8 af[4];
        #pragma unroll
        for (int mt = 0; mt < 4; ++mt)
            af[mt] = *(const bf16x8*)&Ah[wm * 64 + mt * 16 + l15][lg * 8];
        #pragma unroll
        for (int nt = 0; nt < 4; ++nt) {
            bf16x8 bfh = *(const bf16x8*)&Bh[wn * 64 + nt * 16 + l15][lg * 8];
            bf16x8 bfl = *(const bf16x8*)&Bl[wn * 64 + nt * 16 + l15][lg * 8];
            #pragma unroll
            for (int mt = 0; mt < 4; ++mt) {
                acc[mt][nt] = mfma16(af[mt], bfh, acc[mt][nt]);
                acc[mt][nt] = mfma16(af[mt], bfl, acc[mt][nt]);
            }
        }
    }

    const float* bias = z == 0 ? bq : z == 1 ? bk : bv;
    #pragma unroll
    for (int nt = 0; nt < 4; ++nt) {
        const int n = n0 + wn * 64 + nt * 16 + l15;
        const float bz = bias[n];
        #pragma unroll
        for (int mt = 0; mt < 4; ++mt) {
            if (z == 2) {
                bf16x4 v4;
                int mbase = m0 + wm * 64 + mt * 16 + lg * 4;
                #pragma unroll
                for (int rr = 0; rr < 4; ++rr)
                    v4[rr] = (__bf16)(acc[mt][nt][rr] + bz);
                int bb = mbase >> 10, s = mbase & 1023, h = n >> 6, d = n & 63;
                *(bf16x4*)(vo + ((size_t)(bb * HH + h) * 64 + d) * SS + s) = v4;
            } else {
                #pragma unroll
                for (int rr = 0; rr < 4; ++rr) {
                    int m = m0 + wm * 64 + mt * 16 + lg * 4 + rr;
                    float v = acc[mt][nt][rr] + bz;
                    int bb = m >> 10, s = m & 1023, h = n >> 6, d = n & 63;
                    __bf16* outp = z == 0 ? qo : ko;
                    outp[((size_t)(bb * HH + h) * SS + s) * 64 + d] = (__bf16)v;
                }
            }
        }
    }
}

// ---------------- final GEMM: out = ctx(hi/lo) @ Wo + bo (128x128 tile) ----------------
__global__ __launch_bounds__(256, 3) void gemm_out2(
    const __bf16* __restrict__ Ahig, const __bf16* __restrict__ Alog,
    const __bf16* __restrict__ Wth, const __bf16* __restrict__ Wtl,
    const float* __restrict__ bias, float* __restrict__ Cf)
{
    __shared__ __align__(16) __bf16 Ah[BM][LD];
    __shared__ __align__(16) __bf16 Al[BM][LD];
    __shared__ __align__(16) __bf16 Bh[BN][LD];
    __shared__ __align__(16) __bf16 Bl[BN][LD];

    const int tid = threadIdx.x;
    const int w = tid >> 6, lane = tid & 63, l15 = lane & 15, lg = lane >> 4;
    const int wm = w >> 1, wn = w & 1;
    const int n0 = blockIdx.x * BN;
    const int m0 = blockIdx.y * BM;
    const __bf16* wh = Wth + (size_t)3 * 512 * 512;
    const __bf16* wl = Wtl + (size_t)3 * 512 * 512;

    f32x4 acc[4][4];
    #pragma unroll
    for (int i = 0; i < 4; ++i)
        #pragma unroll
        for (int j = 0; j < 4; ++j) acc[i][j] = (f32x4){0.f, 0.f, 0.f, 0.f};

    for (int k0 = 0; k0 < 512; k0 += BK) {
        __syncthreads();
        {
            const int row = tid >> 2, c = (tid & 3) * 8;
            #pragma unroll
            for (int p = 0; p < 2; ++p) {
                int rr = row + p * 64;
                *(bf16x8*)&Ah[rr][c] =
                    *(const bf16x8*)(Ahig + (size_t)(m0 + rr) * 512 + k0 + c);
                *(bf16x8*)&Al[rr][c] =
                    *(const bf16x8*)(Alog + (size_t)(m0 + rr) * 512 + k0 + c);
            }
        }
        {
            const int row = tid >> 2, c = (tid & 3) * 8;
            #pragma unroll
            for (int p = 0; p < 2; ++p) {
                int rr = row + p * 64;
                *(bf16x8*)&Bh[rr][c] =
                    *(const bf16x8*)(wh + (size_t)(n0 + rr) * 512 + k0 + c);
                *(bf16x8*)&Bl[rr][c] =
                    *(const bf16x8*)(wl + (size_t)(n0 + rr) * 512 + k0 + c);
            }
        }
        __syncthreads();

        bf16x8 afh[4], afl[4];
        #pragma unroll
        for (int mt = 0; mt < 4; ++mt) {
            afh[mt] = *(const bf16x8*)&Ah[wm * 64 + mt * 16 + l15][lg * 8];
            afl[mt] = *(const bf16x8*)&Al[wm * 64 + mt * 16 + l15][lg * 8];
        }
        #pragma unroll
        for (int nt = 0; nt < 4; ++nt) {
            bf16x8 bfh = *(const bf16x8*)&Bh[wn * 64 + nt * 16 + l15][lg * 8];
            bf16x8 bfl = *(const bf16x8*)&Bl[wn * 64 + nt * 16 + l15][lg * 8];
            #pragma unroll
            for (int mt = 0; mt < 4; ++mt) {
                acc[mt][nt] = mfma16(afh[mt], bfh, acc[mt][nt]);
                acc[mt][nt] = mfma16(afh[mt], bfl, acc[mt][nt]);
                acc[mt][nt] = mfma16(afl[mt], bfh, acc[mt][nt]);
            }
        }
    }
    #pragma unroll
    for (int nt = 0; nt < 4; ++nt) {
        int n = n0 + wn * 64 + nt * 16 + l15;
        float bz = bias[n];
        #pragma unroll
        for (int rr = 0; rr < 4; ++rr) {
            #pragma unroll
            for (int mt = 0; mt < 4; ++mt) {
                int m = m0 + wm * 64 + mt * 16 + lg * 4 + rr;
                Cf[(size_t)m * 512 + n] = acc[mt][nt][rr] + bz;
            }
        }
    }
}

// ---------------- G precompute ----------------
__global__ __launch_bounds__(256) void gprep(
    const float* __restrict__ mask, const float* __restrict__ adj,
    const float* __restrict__ dist,
    __bf16* __restrict__ Gg, float* __restrict__ rowILg)
{
    const int w = threadIdx.x >> 6, lane = threadIdx.x & 63;
    const int row = blockIdx.x * 4 + w;
    const int b = row >> 10;
    const size_t drow = (size_t)row * SS;
    const float L2E = 1.44269504f;
    const float* mrow = mask + (size_t)b * SS;
    float sm = 0.f;
    #pragma unroll
    for (int j = 0; j < 4; ++j) {
        int c = lane * 4 + j * 256;
        f32x4 d4 = *(const f32x4*)(dist + drow + c);
        f32x4 a4 = *(const f32x4*)(adj + drow + c);
        f32x4 m4 = *(const f32x4*)(mrow + c);
        bf16x4 g4;
        #pragma unroll
        for (int r = 0; r < 4; ++r) {
            float e = exp2f(fmaf(m4[r], -1e9f * L2E, fmaf(d4[r], L2E, -L2E)));
            sm += e;
            g4[r] = (__bf16)(a4[r] * e);
        }
        *(bf16x4*)(Gg + drow + c) = g4;
    }
    #pragma unroll
    for (int off = 1; off <= 32; off <<= 1)
        sm += __shfl_xor(sm, off, 64);
    if (lane == 0) rowILg[row] = 1.0f / sm;
}

// ---------------- Fused attention v10 (r15, known-good): staged + T14 ----------------
__global__ __launch_bounds__(512, 4) void attn10(
    const __bf16* __restrict__ qh_, const __bf16* __restrict__ kh,
    const __bf16* __restrict__ vt,
    const float* __restrict__ mask, const __bf16* __restrict__ Gg,
    const float* __restrict__ rowILg,
    float* __restrict__ attn_out, __bf16* __restrict__ chi, __bf16* __restrict__ clo)
{
    __shared__ float nmb[1024];                        // 4 KB
    __shared__ __align__(16) __bf16 P[32][1024];       // 64 KB, swizzled
    __shared__ __align__(16) __bf16 KV[64][64];        // 8 KB chunk buffer, swizzled
    __shared__ float redl[8][16];

    const int tid = threadIdx.x;
    const int w = tid >> 6, lane = tid & 63, l15 = lane & 15, lg = lane >> 4;
    const int bid = blockIdx.x;
    const int h = bid & 7;
    const int b = (bid >> 3) & 7;
    const int q0 = (bid >> 6) * 32;
    const float L2E = 1.44269504f;
    const float c1 = 0.125f * L2E;

    char* Pb = (char*)P;
    char* KVb = (char*)KV;
    const int srow = tid >> 3;               // staging row (64 rows, 8 thr/row)
    const int scol = (tid & 7) * 8;          // staging elem offset within row
    const int sdst = srow * 128 + ((scol * 2) ^ ((srow & 7) << 4));

    #pragma unroll
    for (int i = 0; i < 2; ++i) {
        int c = tid + 512 * i;
        nmb[c] = fmaf(mask[(size_t)b * SS + c], -1e9f * L2E, -16.0f * L2E);
    }

    const size_t hb = ((size_t)(b * HH + h)) * SS * 64;
    const int qsub = w >> 2, ktw = w & 3;
    bf16x8 qf0 = *(const bf16x8*)(qh_ + hb + (size_t)(q0 + qsub * 16 + l15) * 64 + lg * 8);
    bf16x8 qf1 = *(const bf16x8*)(qh_ + hb + (size_t)(q0 + qsub * 16 + l15) * 64 + 32 + lg * 8);

    const int krow = ktw * 16 + l15;                       // K fragment row in chunk
    const int kswz = (krow & 7) << 4;
    const int prow = qsub * 16 + l15;                      // P row (q)
    const int pswz = (prow & 7) << 4;

    // ---- pass 1: 16 chunks of 64 keys, register-pipelined staging ----
    const __bf16* kcp = kh + hb + (size_t)srow * 64 + scol;
    bf16x8 kvreg = *(const bf16x8*)kcp;                    // chunk 0
    float lac = 0.f;
    for (int c = 0; c < 16; ++c) {
        __syncthreads();                                   // KV free
        *(bf16x8*)(KVb + sdst) = kvreg;                    // write chunk c
        __syncthreads();                                   // KV ready
        if (c + 1 < 16)
            kvreg = *(const bf16x8*)(kcp + (size_t)(c + 1) * 4096);  // 64 rows x 64 elems
        bf16x8 k0v = *(const bf16x8*)(KVb + krow * 128 + ((lg * 16) ^ kswz));
        bf16x8 k1v = *(const bf16x8*)(KVb + krow * 128 + ((64 + lg * 16) ^ kswz));
        f32x4 acc = {0.f, 0.f, 0.f, 0.f};
        acc = mfma16(k0v, qf0, acc);
        acc = mfma16(k1v, qf1, acc);
        const int key4 = c * 64 + ktw * 16 + lg * 4;
        f32x4 nb4 = *(const f32x4*)&nmb[key4];
        float e0 = exp2f(fmaf(acc[0], c1, nb4[0]));
        float e1 = exp2f(fmaf(acc[1], c1, nb4[1]));
        float e2 = exp2f(fmaf(acc[2], c1, nb4[2]));
        float e3 = exp2f(fmaf(acc[3], c1, nb4[3]));
        lac += (e0 + e1) + (e2 + e3);
        bf16x4 pb;
        pb[0] = (__bf16)e0; pb[1] = (__bf16)e1;
        pb[2] = (__bf16)e2; pb[3] = (__bf16)e3;
        *(bf16x4*)(Pb + prow * 2048 + ((key4 * 2) ^ pswz)) = pb;
    }
    #pragma unroll
    for (int off = 16; off <= 32; off <<= 1)
        lac += __shfl_xor(lac, off, 64);
    if (lg == 0) redl[w][l15] = lac;
    __syncthreads();

    // ---- gate phase: wave w -> q-rows [4w, 4w+4); G coalesced; fold coef ----
    const float* rg = rowILg + (size_t)b * SS + q0;
    float* aoutb = attn_out + ((size_t)(b * HH + h)) * SS * SS;
    const __bf16* gb = Gg + ((size_t)b * SS + q0) * SS;
    #pragma unroll
    for (int r = 0; r < 4; ++r) {
        const int row = w * 4 + r;
        const int rs = (row >> 4) * 4;
        const float ltot = redl[rs][row & 15] + redl[rs + 1][row & 15]
                         + redl[rs + 2][row & 15] + redl[rs + 3][row & 15];
        const float coefR = rg[row] / ltot;
        const int rswz = (row & 7) << 4;
        float* ar = aoutb + (size_t)(q0 + row) * SS;
        const __bf16* gr = gb + (size_t)row * SS;
        #pragma unroll
        for (int j = 0; j < 4; ++j) {
            const int off = lane * 8 + j * 512;            // bytes within P row
            char* pp = Pb + row * 2048 + (off ^ rswz);
            bf16x4 e4 = *(const bf16x4*)pp;
            bf16x4 g4 = *(const bf16x4*)(gr + (off >> 1));
            f32x4 av;
            bf16x4 pb;
            #pragma unroll
            for (int r2 = 0; r2 < 4; ++r2) {
                float v = (float)e4[r2] * (float)g4[r2] * coefR;
                av[r2] = v;
                pb[r2] = (__bf16)v;
            }
            __builtin_nontemporal_store(av, (f32x4*)(ar + (off >> 1)));
            *(bf16x4*)pp = pb;
        }
    }

    // ---- PV: 8 waves = 2q x 4d; V chunks register-pipelined ----
    const int dh = w & 3;
    const int vrow = dh * 16 + l15;
    const int vswz = (vrow & 7) << 4;
    f32x4 cacc = {0.f, 0.f, 0.f, 0.f};
    const __bf16* vcp = vt + ((size_t)(b * HH + h) * 64 + srow) * SS + scol;
    bf16x8 vreg = *(const bf16x8*)vcp;                     // chunk 0
    for (int c = 0; c < 16; ++c) {
        __syncthreads();                                   // KV free / P gated
        *(bf16x8*)(KVb + sdst) = vreg;
        __syncthreads();                                   // KV ready
        if (c + 1 < 16)
            vreg = *(const bf16x8*)(vcp + (c + 1) * 64);
        #pragma unroll
        for (int ks = 0; ks < 2; ++ks) {
            bf16x8 pa = *(const bf16x8*)(Pb + prow * 2048
                          + ((c * 128 + ks * 64 + lg * 16) ^ pswz));
            bf16x8 vv = *(const bf16x8*)(KVb + vrow * 128 + ((ks * 64 + lg * 16) ^ vswz));
            cacc = mfma16(pa, vv, cacc);
        }
    }

    // ---- epilogue: coef already folded; write ctx hi/lo ----
    #pragma unroll
    for (int r = 0; r < 4; ++r) {
        const int row = qsub * 16 + lg * 4 + r;
        float x = cacc[r];
        __bf16 hv = (__bf16)x;
        size_t idx = ((size_t)b * SS + q0 + row) * DM + h * 64 + dh * 16 + l15;
        chi[idx] = hv;
        clo[idx] = (__bf16)(x - (float)hv);
    }
}

extern "C" void kernel_launch(void* const* d_in, const int* in_sizes, int n_in,
                              void* d_out, int out_size, void* d_ws, size_t ws_size,
                              hipStream_t stream) {
    const float* q    = (const float*)d_in[0];
    const float* k    = (const float*)d_in[1];
    const float* v    = (const float*)d_in[2];
    const float* mask = (const float*)d_in[3];
    const float* adj  = (const float*)d_in[4];
    const float* dist = (const float*)d_in[5];
    const float* Wq   = (const float*)d_in[6];
    const float* bq   = (const float*)d_in[7];
    const float* Wk   = (const float*)d_in[8];
    const float* bk   = (const float*)d_in[9];
    const float* Wv   = (const float*)d_in[10];
    const float* bv   = (const float*)d_in[11];
    const float* Wo   = (const float*)d_in[12];
    const float* bo   = (const float*)d_in[13];

    const size_t NT = (size_t)BB * SS * DM;   // 4,194,304
    const size_t WN = 512 * 512;
    const size_t NSS = (size_t)BB * SS * SS;  // 8,388,608
    __bf16* wth = (__bf16*)d_ws;
    __bf16* wtl = wth + 4 * WN;
    __bf16* qhb = wtl + 4 * WN;
    __bf16* khb = qhb + NT;
    __bf16* vtb = khb + NT;
    __bf16* chi = vtb + NT;
    __bf16* clo = chi + NT;
    __bf16* Gg  = clo + NT;
    float* rowILg = (float*)(Gg + NSS);

    float* outp = (float*)d_out;
    float* attn = outp + NT;

    wconv<<<dim3(8, 8, 4), 256, 0, stream>>>(Wq, Wk, Wv, Wo, wth, wtl);

    gprep<<<2048, 256, 0, stream>>>(mask, adj, dist, Gg, rowILg);

    gemm_qkv2<<<dim3(6, 64), 512, 0, stream>>>(
        q, k, v, wth, wtl, bq, bk, bv, qhb, khb, vtb);

    attn10<<<2048, 512, 0, stream>>>(qhb, khb, vtb, mask, Gg, rowILg, attn, chi, clo);

    gemm_out2<<<dim3(4, 64), 256, 0, stream>>>(
        chi, clo, wth, wtl, bo, outp);
}

// Round 18
// 185.419 us; speedup vs baseline: 1.1142x; 1.0481x over previous
//
#include <hip/hip_runtime.h>
#include <hip/hip_bf16.h>

#define BB 8
#define SS 1024
#define DM 512
#define HH 8
#define BM 128
#define BN 128
#define BK 32
#define LD 40   // LDS row stride (bf16 elems): 80 B = 16B-aligned, 2-way banks

typedef __bf16 bf16x8 __attribute__((ext_vector_type(8)));
typedef __bf16 bf16x4 __attribute__((ext_vector_type(4)));
typedef float f32x4 __attribute__((ext_vector_type(4)));

__device__ __forceinline__ f32x4 mfma16(bf16x8 a, bf16x8 b, f32x4 c) {
    return __builtin_amdgcn_mfma_f32_16x16x32_bf16(a, b, c, 0, 0, 0);
}

// ---------------- W transpose + hi/lo split ----------------
__global__ __launch_bounds__(256) void wconv(
    const float* __restrict__ W0, const float* __restrict__ W1,
    const float* __restrict__ W2, const float* __restrict__ W3,
    __bf16* __restrict__ th, __bf16* __restrict__ tl)
{
    const float* W = blockIdx.z == 0 ? W0 : blockIdx.z == 1 ? W1
                   : blockIdx.z == 2 ? W2 : W3;
    __bf16* oh = th + (size_t)blockIdx.z * 512 * 512;
    __bf16* ol = tl + (size_t)blockIdx.z * 512 * 512;
    __shared__ float T[64][65];
    const int k0 = blockIdx.x * 64, n0 = blockIdx.y * 64;
    const int r = threadIdx.x >> 4, c4 = (threadIdx.x & 15) * 4;
    #pragma unroll
    for (int p = 0; p < 4; ++p) {
        float4 v = *(const float4*)(W + (size_t)(k0 + p * 16 + r) * 512 + n0 + c4);
        T[p * 16 + r][c4 + 0] = v.x; T[p * 16 + r][c4 + 1] = v.y;
        T[p * 16 + r][c4 + 2] = v.z; T[p * 16 + r][c4 + 3] = v.w;
    }
    __syncthreads();
    #pragma unroll
    for (int p = 0; p < 4; ++p) {
        int n = n0 + p * 16 + r;
        bf16x4 h4, l4;
        #pragma unroll
        for (int j = 0; j < 4; ++j) {
            float x = T[c4 + j][p * 16 + r];
            __bf16 h = (__bf16)x;
            h4[j] = h; l4[j] = (__bf16)(x - (float)h);
        }
        *(bf16x4*)(oh + (size_t)n * 512 + k0 + c4) = h4;
        *(bf16x4*)(ol + (size_t)n * 512 + k0 + c4) = l4;
    }
}

// ---------------- Fused QKV GEMM (BN=256) + gprep, one dispatch ----------------
// blocks [0,384): QKV projection (z = (bx%6)>>1, n0 = ((bx%6)&1)*256, m0 = (bx/6)*128)
// blocks [384,1408): G precompute, 8 waves x 1 row each.
__global__ __launch_bounds__(512, 4) void qkv_gprep(
    const float* __restrict__ Aq, const float* __restrict__ Ak,
    const float* __restrict__ Av,
    const __bf16* __restrict__ Wth, const __bf16* __restrict__ Wtl,
    const float* __restrict__ bq, const float* __restrict__ bk,
    const float* __restrict__ bv,
    __bf16* __restrict__ qo, __bf16* __restrict__ ko, __bf16* __restrict__ vo,
    const float* __restrict__ mask, const float* __restrict__ adj,
    const float* __restrict__ dist,
    __bf16* __restrict__ Gg, float* __restrict__ rowILg)
{
    __shared__ __align__(16) __bf16 Ah[128][LD];
    __shared__ __align__(16) __bf16 Bh[256][LD];
    __shared__ __align__(16) __bf16 Bl[256][LD];

    const int tid = threadIdx.x;
    const int w = tid >> 6, lane = tid & 63, l15 = lane & 15, lg = lane >> 4;

    if (blockIdx.x >= 384) {
        // ---- gprep: row = (bid-384)*8 + w ----
        const int row = (blockIdx.x - 384) * 8 + w;
        const int b = row >> 10;
        const size_t drow = (size_t)row * SS;
        const float L2E = 1.44269504f;
        const float* mrow = mask + (size_t)b * SS;
        float sm = 0.f;
        #pragma unroll
        for (int j = 0; j < 4; ++j) {
            int c = lane * 4 + j * 256;
            f32x4 d4 = *(const f32x4*)(dist + drow + c);
            f32x4 a4 = *(const f32x4*)(adj + drow + c);
            f32x4 m4 = *(const f32x4*)(mrow + c);
            bf16x4 g4;
            #pragma unroll
            for (int r = 0; r < 4; ++r) {
                float e = exp2f(fmaf(m4[r], -1e9f * L2E, fmaf(d4[r], L2E, -L2E)));
                sm += e;
                g4[r] = (__bf16)(a4[r] * e);
            }
            *(bf16x4*)(Gg + drow + c) = g4;
        }
        #pragma unroll
        for (int off = 1; off <= 32; off <<= 1)
            sm += __shfl_xor(sm, off, 64);
        if (lane == 0) rowILg[row] = 1.0f / sm;
        return;
    }

    // ---- QKV GEMM ----
    const int wm = w >> 2, wn = w & 3;
    const int bx = blockIdx.x % 6;
    const int z  = bx >> 1;
    const int n0 = (bx & 1) * 256;
    const int m0 = (blockIdx.x / 6) * 128;

    const float* Afp = z == 0 ? Aq : z == 1 ? Ak : Av;
    const __bf16* wh = Wth + (size_t)z * 512 * 512;
    const __bf16* wl = Wtl + (size_t)z * 512 * 512;

    f32x4 acc[4][4];
    #pragma unroll
    for (int i = 0; i < 4; ++i)
        #pragma unroll
        for (int j = 0; j < 4; ++j) acc[i][j] = (f32x4){0.f, 0.f, 0.f, 0.f};

    const int arow = tid >> 2, ac = (tid & 3) * 8;       // A stage: 4 thr/row
    const int wrow = tid >> 1, wc = (tid & 1) * 16;      // W stage: 2 thr/row

    for (int k0 = 0; k0 < 512; k0 += BK) {
        __syncthreads();
        {   // stage A: 128 x 32 fp32 -> bf16
            const float* ap = Afp + (size_t)(m0 + arow) * 512 + k0 + ac;
            f32x4 a0 = *(const f32x4*)ap;
            f32x4 a1 = *(const f32x4*)(ap + 4);
            bf16x8 h8;
            #pragma unroll
            for (int j = 0; j < 4; ++j) { h8[j] = (__bf16)a0[j]; h8[4 + j] = (__bf16)a1[j]; }
            *(bf16x8*)&Ah[arow][ac] = h8;
        }
        {   // stage W: 256 x 32, hi + lo
            const __bf16* wp = wh + (size_t)(n0 + wrow) * 512 + k0 + wc;
            const __bf16* lp = wl + (size_t)(n0 + wrow) * 512 + k0 + wc;
            *(bf16x8*)&Bh[wrow][wc]     = *(const bf16x8*)wp;
            *(bf16x8*)&Bh[wrow][wc + 8] = *(const bf16x8*)(wp + 8);
            *(bf16x8*)&Bl[wrow][wc]     = *(const bf16x8*)lp;
            *(bf16x8*)&Bl[wrow][wc + 8] = *(const bf16x8*)(lp + 8);
        }
        __syncthreads();

        bf16x8 af[4];
        #pragma unroll
        for (int mt = 0; mt < 4; ++mt)
            af[mt] = *(const bf16x8*)&Ah[wm * 64 + mt * 16 + l15][lg * 8];
        #pragma unroll
        for (int nt = 0; nt < 4; ++nt) {
            bf16x8 bfh = *(const bf16x8*)&Bh[wn * 64 + nt * 16 + l15][lg * 8];
            bf16x8 bfl = *(const bf16x8*)&Bl[wn * 64 + nt * 16 + l15][lg * 8];
            #pragma unroll
            for (int mt = 0; mt < 4; ++mt) {
                acc[mt][nt] = mfma16(af[mt], bfh, acc[mt][nt]);
                acc[mt][nt] = mfma16(af[mt], bfl, acc[mt][nt]);
            }
        }
    }

    const float* bias = z == 0 ? bq : z == 1 ? bk : bv;
    #pragma unroll
    for (int nt = 0; nt < 4; ++nt) {
        const int n = n0 + wn * 64 + nt * 16 + l15;
        const float bz = bias[n];
        #pragma unroll
        for (int mt = 0; mt < 4; ++mt) {
            if (z == 2) {
                bf16x4 v4;
                int mbase = m0 + wm * 64 + mt * 16 + lg * 4;
                #pragma unroll
                for (int rr = 0; rr < 4; ++rr)
                    v4[rr] = (__bf16)(acc[mt][nt][rr] + bz);
                int bb = mbase >> 10, s = mbase & 1023, h = n >> 6, d = n & 63;
                *(bf16x4*)(vo + ((size_t)(bb * HH + h) * 64 + d) * SS + s) = v4;
            } else {
                #pragma unroll
                for (int rr = 0; rr < 4; ++rr) {
                    int m = m0 + wm * 64 + mt * 16 + lg * 4 + rr;
                    float v = acc[mt][nt][rr] + bz;
                    int bb = m >> 10, s = m & 1023, h = n >> 6, d = n & 63;
                    __bf16* outp = z == 0 ? qo : ko;
                    outp[((size_t)(bb * HH + h) * SS + s) * 64 + d] = (__bf16)v;
                }
            }
        }
    }
}

// ---------------- final GEMM: out = ctx(hi/lo) @ Wo + bo (128x128 tile) ----------------
__global__ __launch_bounds__(256, 3) void gemm_out2(
    const __bf16* __restrict__ Ahig, const __bf16* __restrict__ Alog,
    const __bf16* __restrict__ Wth, const __bf16* __restrict__ Wtl,
    const float* __restrict__ bias, float* __restrict__ Cf)
{
    __shared__ __align__(16) __bf16 Ah[BM][LD];
    __shared__ __align__(16) __bf16 Al[BM][LD];
    __shared__ __align__(16) __bf16 Bh[BN][LD];
    __shared__ __align__(16) __bf16 Bl[BN][LD];

    const int tid = threadIdx.x;
    const int w = tid >> 6, lane = tid & 63, l15 = lane & 15, lg = lane >> 4;
    const int wm = w >> 1, wn = w & 1;
    const int n0 = blockIdx.x * BN;
    const int m0 = blockIdx.y * BM;
    const __bf16* wh = Wth + (size_t)3 * 512 * 512;
    const __bf16* wl = Wtl + (size_t)3 * 512 * 512;

    f32x4 acc[4][4];
    #pragma unroll
    for (int i = 0; i < 4; ++i)
        #pragma unroll
        for (int j = 0; j < 4; ++j) acc[i][j] = (f32x4){0.f, 0.f, 0.f, 0.f};

    for (int k0 = 0; k0 < 512; k0 += BK) {
        __syncthreads();
        {
            const int row = tid >> 2, c = (tid & 3) * 8;
            #pragma unroll
            for (int p = 0; p < 2; ++p) {
                int rr = row + p * 64;
                *(bf16x8*)&Ah[rr][c] =
                    *(const bf16x8*)(Ahig + (size_t)(m0 + rr) * 512 + k0 + c);
                *(bf16x8*)&Al[rr][c] =
                    *(const bf16x8*)(Alog + (size_t)(m0 + rr) * 512 + k0 + c);
            }
        }
        {
            const int row = tid >> 2, c = (tid & 3) * 8;
            #pragma unroll
            for (int p = 0; p < 2; ++p) {
                int rr = row + p * 64;
                *(bf16x8*)&Bh[rr][c] =
                    *(const bf16x8*)(wh + (size_t)(n0 + rr) * 512 + k0 + c);
                *(bf16x8*)&Bl[rr][c] =
                    *(const bf16x8*)(wl + (size_t)(n0 + rr) * 512 + k0 + c);
            }
        }
        __syncthreads();

        bf16x8 afh[4], afl[4];
        #pragma unroll
        for (int mt = 0; mt < 4; ++mt) {
            afh[mt] = *(const bf16x8*)&Ah[wm * 64 + mt * 16 + l15][lg * 8];
            afl[mt] = *(const bf16x8*)&Al[wm * 64 + mt * 16 + l15][lg * 8];
        }
        #pragma unroll
        for (int nt = 0; nt < 4; ++nt) {
            bf16x8 bfh = *(const bf16x8*)&Bh[wn * 64 + nt * 16 + l15][lg * 8];
            bf16x8 bfl = *(const bf16x8*)&Bl[wn * 64 + nt * 16 + l15][lg * 8];
            #pragma unroll
            for (int mt = 0; mt < 4; ++mt) {
                acc[mt][nt] = mfma16(afh[mt], bfh, acc[mt][nt]);
                acc[mt][nt] = mfma16(afh[mt], bfl, acc[mt][nt]);
                acc[mt][nt] = mfma16(afl[mt], bfh, acc[mt][nt]);
            }
        }
    }
    #pragma unroll
    for (int nt = 0; nt < 4; ++nt) {
        int n = n0 + wn * 64 + nt * 16 + l15;
        float bz = bias[n];
        #pragma unroll
        for (int rr = 0; rr < 4; ++rr) {
            #pragma unroll
            for (int mt = 0; mt < 4; ++mt) {
                int m = m0 + wm * 64 + mt * 16 + lg * 4 + rr;
                Cf[(size_t)m * 512 + n] = acc[mt][nt][rr] + bz;
            }
        }
    }
}

// ---------------- Fused attention v10 (r15, known-good): staged + T14 ----------------
__global__ __launch_bounds__(512, 4) void attn10(
    const __bf16* __restrict__ qh_, const __bf16* __restrict__ kh,
    const __bf16* __restrict__ vt,
    const float* __restrict__ mask, const __bf16* __restrict__ Gg,
    const float* __restrict__ rowILg,
    float* __restrict__ attn_out, __bf16* __restrict__ chi, __bf16* __restrict__ clo)
{
    __shared__ float nmb[1024];                        // 4 KB
    __shared__ __align__(16) __bf16 P[32][1024];       // 64 KB, swizzled
    __shared__ __align__(16) __bf16 KV[64][64];        // 8 KB chunk buffer, swizzled
    __shared__ float redl[8][16];

    const int tid = threadIdx.x;
    const int w = tid >> 6, lane = tid & 63, l15 = lane & 15, lg = lane >> 4;
    const int bid = blockIdx.x;
    const int h = bid & 7;
    const int b = (bid >> 3) & 7;
    const int q0 = (bid >> 6) * 32;
    const float L2E = 1.44269504f;
    const float c1 = 0.125f * L2E;

    char* Pb = (char*)P;
    char* KVb = (char*)KV;
    const int srow = tid >> 3;               // staging row (64 rows, 8 thr/row)
    const int scol = (tid & 7) * 8;          // staging elem offset within row
    const int sdst = srow * 128 + ((scol * 2) ^ ((srow & 7) << 4));

    #pragma unroll
    for (int i = 0; i < 2; ++i) {
        int c = tid + 512 * i;
        nmb[c] = fmaf(mask[(size_t)b * SS + c], -1e9f * L2E, -16.0f * L2E);
    }

    const size_t hb = ((size_t)(b * HH + h)) * SS * 64;
    const int qsub = w >> 2, ktw = w & 3;
    bf16x8 qf0 = *(const bf16x8*)(qh_ + hb + (size_t)(q0 + qsub * 16 + l15) * 64 + lg * 8);
    bf16x8 qf1 = *(const bf16x8*)(qh_ + hb + (size_t)(q0 + qsub * 16 + l15) * 64 + 32 + lg * 8);

    const int krow = ktw * 16 + l15;                       // K fragment row in chunk
    const int kswz = (krow & 7) << 4;
    const int prow = qsub * 16 + l15;                      // P row (q)
    const int pswz = (prow & 7) << 4;

    // ---- pass 1: 16 chunks of 64 keys, register-pipelined staging ----
    const __bf16* kcp = kh + hb + (size_t)srow * 64 + scol;
    bf16x8 kvreg = *(const bf16x8*)kcp;                    // chunk 0
    float lac = 0.f;
    for (int c = 0; c < 16; ++c) {
        __syncthreads();                                   // KV free
        *(bf16x8*)(KVb + sdst) = kvreg;                    // write chunk c
        __syncthreads();                                   // KV ready
        if (c + 1 < 16)
            kvreg = *(const bf16x8*)(kcp + (size_t)(c + 1) * 4096);  // 64 rows x 64 elems
        bf16x8 k0v = *(const bf16x8*)(KVb + krow * 128 + ((lg * 16) ^ kswz));
        bf16x8 k1v = *(const bf16x8*)(KVb + krow * 128 + ((64 + lg * 16) ^ kswz));
        f32x4 acc = {0.f, 0.f, 0.f, 0.f};
        acc = mfma16(k0v, qf0, acc);
        acc = mfma16(k1v, qf1, acc);
        const int key4 = c * 64 + ktw * 16 + lg * 4;
        f32x4 nb4 = *(const f32x4*)&nmb[key4];
        float e0 = exp2f(fmaf(acc[0], c1, nb4[0]));
        float e1 = exp2f(fmaf(acc[1], c1, nb4[1]));
        float e2 = exp2f(fmaf(acc[2], c1, nb4[2]));
        float e3 = exp2f(fmaf(acc[3], c1, nb4[3]));
        lac += (e0 + e1) + (e2 + e3);
        bf16x4 pb;
        pb[0] = (__bf16)e0; pb[1] = (__bf16)e1;
        pb[2] = (__bf16)e2; pb[3] = (__bf16)e3;
        *(bf16x4*)(Pb + prow * 2048 + ((key4 * 2) ^ pswz)) = pb;
    }
    #pragma unroll
    for (int off = 16; off <= 32; off <<= 1)
        lac += __shfl_xor(lac, off, 64);
    if (lg == 0) redl[w][l15] = lac;
    __syncthreads();

    // ---- gate phase: wave w -> q-rows [4w, 4w+4); G coalesced; fold coef ----
    const float* rg = rowILg + (size_t)b * SS + q0;
    float* aoutb = attn_out + ((size_t)(b * HH + h)) * SS * SS;
    const __bf16* gb = Gg + ((size_t)b * SS + q0) * SS;
    #pragma unroll
    for (int r = 0; r < 4; ++r) {
        const int row = w * 4 + r;
        const int rs = (row >> 4) * 4;
        const float ltot = redl[rs][row & 15] + redl[rs + 1][row & 15]
                         + redl[rs + 2][row & 15] + redl[rs + 3][row & 15];
        const float coefR = rg[row] / ltot;
        const int rswz = (row & 7) << 4;
        float* ar = aoutb + (size_t)(q0 + row) * SS;
        const __bf16* gr = gb + (size_t)row * SS;
        #pragma unroll
        for (int j = 0; j < 4; ++j) {
            const int off = lane * 8 + j * 512;            // bytes within P row
            char* pp = Pb + row * 2048 + (off ^ rswz);
            bf16x4 e4 = *(const bf16x4*)pp;
            bf16x4 g4 = *(const bf16x4*)(gr + (off >> 1));
            f32x4 av;
            bf16x4 pb;
            #pragma unroll
            for (int r2 = 0; r2 < 4; ++r2) {
                float v = (float)e4[r2] * (float)g4[r2] * coefR;
                av[r2] = v;
                pb[r2] = (__bf16)v;
            }
            __builtin_nontemporal_store(av, (f32x4*)(ar + (off >> 1)));
            *(bf16x4*)pp = pb;
        }
    }

    // ---- PV: 8 waves = 2q x 4d; V chunks register-pipelined ----
    const int dh = w & 3;
    const int vrow = dh * 16 + l15;
    const int vswz = (vrow & 7) << 4;
    f32x4 cacc = {0.f, 0.f, 0.f, 0.f};
    const __bf16* vcp = vt + ((size_t)(b * HH + h) * 64 + srow) * SS + scol;
    bf16x8 vreg = *(const bf16x8*)vcp;                     // chunk 0
    for (int c = 0; c < 16; ++c) {
        __syncthreads();                                   // KV free / P gated
        *(bf16x8*)(KVb + sdst) = vreg;
        __syncthreads();                                   // KV ready
        if (c + 1 < 16)
            vreg = *(const bf16x8*)(vcp + (c + 1) * 64);
        #pragma unroll
        for (int ks = 0; ks < 2; ++ks) {
            bf16x8 pa = *(const bf16x8*)(Pb + prow * 2048
                          + ((c * 128 + ks * 64 + lg * 16) ^ pswz));
            bf16x8 vv = *(const bf16x8*)(KVb + vrow * 128 + ((ks * 64 + lg * 16) ^ vswz));
            cacc = mfma16(pa, vv, cacc);
        }
    }

    // ---- epilogue: coef already folded; write ctx hi/lo ----
    #pragma unroll
    for (int r = 0; r < 4; ++r) {
        const int row = qsub * 16 + lg * 4 + r;
        float x = cacc[r];
        __bf16 hv = (__bf16)x;
        size_t idx = ((size_t)b * SS + q0 + row) * DM + h * 64 + dh * 16 + l15;
        chi[idx] = hv;
        clo[idx] = (__bf16)(x - (float)hv);
    }
}

extern "C" void kernel_launch(void* const* d_in, const int* in_sizes, int n_in,
                              void* d_out, int out_size, void* d_ws, size_t ws_size,
                              hipStream_t stream) {
    const float* q    = (const float*)d_in[0];
    const float* k    = (const float*)d_in[1];
    const float* v    = (const float*)d_in[2];
    const float* mask = (const float*)d_in[3];
    const float* adj  = (const float*)d_in[4];
    const float* dist = (const float*)d_in[5];
    const float* Wq   = (const float*)d_in[6];
    const float* bq   = (const float*)d_in[7];
    const float* Wk   = (const float*)d_in[8];
    const float* bk   = (const float*)d_in[9];
    const float* Wv   = (const float*)d_in[10];
    const float* bv   = (const float*)d_in[11];
    const float* Wo   = (const float*)d_in[12];
    const float* bo   = (const float*)d_in[13];

    const size_t NT = (size_t)BB * SS * DM;   // 4,194,304
    const size_t WN = 512 * 512;
    const size_t NSS = (size_t)BB * SS * SS;  // 8,388,608
    __bf16* wth = (__bf16*)d_ws;
    __bf16* wtl = wth + 4 * WN;
    __bf16* qhb = wtl + 4 * WN;
    __bf16* khb = qhb + NT;
    __bf16* vtb = khb + NT;
    __bf16* chi = vtb + NT;
    __bf16* clo = chi + NT;
    __bf16* Gg  = clo + NT;
    float* rowILg = (float*)(Gg + NSS);

    float* outp = (float*)d_out;
    float* attn = outp + NT;

    wconv<<<dim3(8, 8, 4), 256, 0, stream>>>(Wq, Wk, Wv, Wo, wth, wtl);

    qkv_gprep<<<1408, 512, 0, stream>>>(
        q, k, v, wth, wtl, bq, bk, bv, qhb, khb, vtb,
        mask, adj, dist, Gg, rowILg);

    attn10<<<2048, 512, 0, stream>>>(qhb, khb, vtb, mask, Gg, rowILg, attn, chi, clo);

    gemm_out2<<<dim3(4, 64), 256, 0, stream>>>(
        chi, clo, wth, wtl, bo, outp);
}

// Round 19
// 182.549 us; speedup vs baseline: 1.1317x; 1.0157x over previous
//
#include <hip/hip_runtime.h>
#include <hip/hip_bf16.h>

#define BB 8
#define SS 1024
#define DM 512
#define HH 8
#define BM 128
#define BN 128
#define BK 32
#define LD 40   // LDS row stride (bf16 elems): 80 B = 16B-aligned, 2-way banks

typedef __bf16 bf16x8 __attribute__((ext_vector_type(8)));
typedef __bf16 bf16x4 __attribute__((ext_vector_type(4)));
typedef float f32x4 __attribute__((ext_vector_type(4)));

__device__ __forceinline__ f32x4 mfma16(bf16x8 a, bf16x8 b, f32x4 c) {
    return __builtin_amdgcn_mfma_f32_16x16x32_bf16(a, b, c, 0, 0, 0);
}

// ---------------- W transpose + hi/lo split ----------------
__global__ __launch_bounds__(256) void wconv(
    const float* __restrict__ W0, const float* __restrict__ W1,
    const float* __restrict__ W2, const float* __restrict__ W3,
    __bf16* __restrict__ th, __bf16* __restrict__ tl)
{
    const float* W = blockIdx.z == 0 ? W0 : blockIdx.z == 1 ? W1
                   : blockIdx.z == 2 ? W2 : W3;
    __bf16* oh = th + (size_t)blockIdx.z * 512 * 512;
    __bf16* ol = tl + (size_t)blockIdx.z * 512 * 512;
    __shared__ float T[64][65];
    const int k0 = blockIdx.x * 64, n0 = blockIdx.y * 64;
    const int r = threadIdx.x >> 4, c4 = (threadIdx.x & 15) * 4;
    #pragma unroll
    for (int p = 0; p < 4; ++p) {
        float4 v = *(const float4*)(W + (size_t)(k0 + p * 16 + r) * 512 + n0 + c4);
        T[p * 16 + r][c4 + 0] = v.x; T[p * 16 + r][c4 + 1] = v.y;
        T[p * 16 + r][c4 + 2] = v.z; T[p * 16 + r][c4 + 3] = v.w;
    }
    __syncthreads();
    #pragma unroll
    for (int p = 0; p < 4; ++p) {
        int n = n0 + p * 16 + r;
        bf16x4 h4, l4;
        #pragma unroll
        for (int j = 0; j < 4; ++j) {
            float x = T[c4 + j][p * 16 + r];
            __bf16 h = (__bf16)x;
            h4[j] = h; l4[j] = (__bf16)(x - (float)h);
        }
        *(bf16x4*)(oh + (size_t)n * 512 + k0 + c4) = h4;
        *(bf16x4*)(ol + (size_t)n * 512 + k0 + c4) = l4;
    }
}

// ---------------- Fused QKV GEMM (BN=256) + gprep, one dispatch ----------------
__global__ __launch_bounds__(512, 4) void qkv_gprep(
    const float* __restrict__ Aq, const float* __restrict__ Ak,
    const float* __restrict__ Av,
    const __bf16* __restrict__ Wth, const __bf16* __restrict__ Wtl,
    const float* __restrict__ bq, const float* __restrict__ bk,
    const float* __restrict__ bv,
    __bf16* __restrict__ qo, __bf16* __restrict__ ko, __bf16* __restrict__ vo,
    const float* __restrict__ mask, const float* __restrict__ adj,
    const float* __restrict__ dist,
    __bf16* __restrict__ Gg, float* __restrict__ rowILg)
{
    __shared__ __align__(16) __bf16 Ah[128][LD];
    __shared__ __align__(16) __bf16 Bh[256][LD];
    __shared__ __align__(16) __bf16 Bl[256][LD];

    const int tid = threadIdx.x;
    const int w = tid >> 6, lane = tid & 63, l15 = lane & 15, lg = lane >> 4;

    if (blockIdx.x >= 384) {
        const int row = (blockIdx.x - 384) * 8 + w;
        const int b = row >> 10;
        const size_t drow = (size_t)row * SS;
        const float L2E = 1.44269504f;
        const float* mrow = mask + (size_t)b * SS;
        float sm = 0.f;
        #pragma unroll
        for (int j = 0; j < 4; ++j) {
            int c = lane * 4 + j * 256;
            f32x4 d4 = *(const f32x4*)(dist + drow + c);
            f32x4 a4 = *(const f32x4*)(adj + drow + c);
            f32x4 m4 = *(const f32x4*)(mrow + c);
            bf16x4 g4;
            #pragma unroll
            for (int r = 0; r < 4; ++r) {
                float e = exp2f(fmaf(m4[r], -1e9f * L2E, fmaf(d4[r], L2E, -L2E)));
                sm += e;
                g4[r] = (__bf16)(a4[r] * e);
            }
            *(bf16x4*)(Gg + drow + c) = g4;
        }
        #pragma unroll
        for (int off = 1; off <= 32; off <<= 1)
            sm += __shfl_xor(sm, off, 64);
        if (lane == 0) rowILg[row] = 1.0f / sm;
        return;
    }

    const int wm = w >> 2, wn = w & 3;
    const int bx = blockIdx.x % 6;
    const int z  = bx >> 1;
    const int n0 = (bx & 1) * 256;
    const int m0 = (blockIdx.x / 6) * 128;

    const float* Afp = z == 0 ? Aq : z == 1 ? Ak : Av;
    const __bf16* wh = Wth + (size_t)z * 512 * 512;
    const __bf16* wl = Wtl + (size_t)z * 512 * 512;

    f32x4 acc[4][4];
    #pragma unroll
    for (int i = 0; i < 4; ++i)
        #pragma unroll
        for (int j = 0; j < 4; ++j) acc[i][j] = (f32x4){0.f, 0.f, 0.f, 0.f};

    const int arow = tid >> 2, ac = (tid & 3) * 8;
    const int wrow = tid >> 1, wc = (tid & 1) * 16;

    for (int k0 = 0; k0 < 512; k0 += BK) {
        __syncthreads();
        {
            const float* ap = Afp + (size_t)(m0 + arow) * 512 + k0 + ac;
            f32x4 a0 = *(const f32x4*)ap;
            f32x4 a1 = *(const f32x4*)(ap + 4);
            bf16x8 h8;
            #pragma unroll
            for (int j = 0; j < 4; ++j) { h8[j] = (__bf16)a0[j]; h8[4 + j] = (__bf16)a1[j]; }
            *(bf16x8*)&Ah[arow][ac] = h8;
        }
        {
            const __bf16* wp = wh + (size_t)(n0 + wrow) * 512 + k0 + wc;
            const __bf16* lp = wl + (size_t)(n0 + wrow) * 512 + k0 + wc;
            *(bf16x8*)&Bh[wrow][wc]     = *(const bf16x8*)wp;
            *(bf16x8*)&Bh[wrow][wc + 8] = *(const bf16x8*)(wp + 8);
            *(bf16x8*)&Bl[wrow][wc]     = *(const bf16x8*)lp;
            *(bf16x8*)&Bl[wrow][wc + 8] = *(const bf16x8*)(lp + 8);
        }
        __syncthreads();

        bf16x8 af[4];
        #pragma unroll
        for (int mt = 0; mt < 4; ++mt)
            af[mt] = *(const bf16x8*)&Ah[wm * 64 + mt * 16 + l15][lg * 8];
        #pragma unroll
        for (int nt = 0; nt < 4; ++nt) {
            bf16x8 bfh = *(const bf16x8*)&Bh[wn * 64 + nt * 16 + l15][lg * 8];
            bf16x8 bfl = *(const bf16x8*)&Bl[wn * 64 + nt * 16 + l15][lg * 8];
            #pragma unroll
            for (int mt = 0; mt < 4; ++mt) {
                acc[mt][nt] = mfma16(af[mt], bfh, acc[mt][nt]);
                acc[mt][nt] = mfma16(af[mt], bfl, acc[mt][nt]);
            }
        }
    }

    const float* bias = z == 0 ? bq : z == 1 ? bk : bv;
    #pragma unroll
    for (int nt = 0; nt < 4; ++nt) {
        const int n = n0 + wn * 64 + nt * 16 + l15;
        const float bz = bias[n];
        #pragma unroll
        for (int mt = 0; mt < 4; ++mt) {
            if (z == 2) {
                bf16x4 v4;
                int mbase = m0 + wm * 64 + mt * 16 + lg * 4;
                #pragma unroll
                for (int rr = 0; rr < 4; ++rr)
                    v4[rr] = (__bf16)(acc[mt][nt][rr] + bz);
                int bb = mbase >> 10, s = mbase & 1023, h = n >> 6, d = n & 63;
                *(bf16x4*)(vo + ((size_t)(bb * HH + h) * 64 + d) * SS + s) = v4;
            } else {
                #pragma unroll
                for (int rr = 0; rr < 4; ++rr) {
                    int m = m0 + wm * 64 + mt * 16 + lg * 4 + rr;
                    float v = acc[mt][nt][rr] + bz;
                    int bb = m >> 10, s = m & 1023, h = n >> 6, d = n & 63;
                    __bf16* outp = z == 0 ? qo : ko;
                    outp[((size_t)(bb * HH + h) * SS + s) * 64 + d] = (__bf16)v;
                }
            }
        }
    }
}

// ---------------- final GEMM: out = ctx(bf16) @ Wo(hi/lo) + bo ----------------
__global__ __launch_bounds__(256, 3) void gemm_out3(
    const __bf16* __restrict__ Actx,
    const __bf16* __restrict__ Wth, const __bf16* __restrict__ Wtl,
    const float* __restrict__ bias, float* __restrict__ Cf)
{
    __shared__ __align__(16) __bf16 Ah[BM][LD];
    __shared__ __align__(16) __bf16 Bh[BN][LD];
    __shared__ __align__(16) __bf16 Bl[BN][LD];

    const int tid = threadIdx.x;
    const int w = tid >> 6, lane = tid & 63, l15 = lane & 15, lg = lane >> 4;
    const int wm = w >> 1, wn = w & 1;
    const int n0 = blockIdx.x * BN;
    const int m0 = blockIdx.y * BM;
    const __bf16* wh = Wth + (size_t)3 * 512 * 512;
    const __bf16* wl = Wtl + (size_t)3 * 512 * 512;

    f32x4 acc[4][4];
    #pragma unroll
    for (int i = 0; i < 4; ++i)
        #pragma unroll
        for (int j = 0; j < 4; ++j) acc[i][j] = (f32x4){0.f, 0.f, 0.f, 0.f};

    for (int k0 = 0; k0 < 512; k0 += BK) {
        __syncthreads();
        {
            const int row = tid >> 1, c = (tid & 1) * 16;
            *(bf16x8*)&Ah[row][c]     = *(const bf16x8*)(Actx + (size_t)(m0 + row) * 512 + k0 + c);
            *(bf16x8*)&Ah[row][c + 8] = *(const bf16x8*)(Actx + (size_t)(m0 + row) * 512 + k0 + c + 8);
        }
        {
            const int row = tid >> 2, c = (tid & 3) * 8;
            #pragma unroll
            for (int p = 0; p < 2; ++p) {
                int rr = row + p * 64;
                *(bf16x8*)&Bh[rr][c] =
                    *(const bf16x8*)(wh + (size_t)(n0 + rr) * 512 + k0 + c);
                *(bf16x8*)&Bl[rr][c] =
                    *(const bf16x8*)(wl + (size_t)(n0 + rr) * 512 + k0 + c);
            }
        }
        __syncthreads();

        bf16x8 af[4];
        #pragma unroll
        for (int mt = 0; mt < 4; ++mt)
            af[mt] = *(const bf16x8*)&Ah[wm * 64 + mt * 16 + l15][lg * 8];
        #pragma unroll
        for (int nt = 0; nt < 4; ++nt) {
            bf16x8 bfh = *(const bf16x8*)&Bh[wn * 64 + nt * 16 + l15][lg * 8];
            bf16x8 bfl = *(const bf16x8*)&Bl[wn * 64 + nt * 16 + l15][lg * 8];
            #pragma unroll
            for (int mt = 0; mt < 4; ++mt) {
                acc[mt][nt] = mfma16(af[mt], bfh, acc[mt][nt]);
                acc[mt][nt] = mfma16(af[mt], bfl, acc[mt][nt]);
            }
        }
    }
    #pragma unroll
    for (int nt = 0; nt < 4; ++nt) {
        int n = n0 + wn * 64 + nt * 16 + l15;
        float bz = bias[n];
        #pragma unroll
        for (int rr = 0; rr < 4; ++rr) {
            #pragma unroll
            for (int mt = 0; mt < 4; ++mt) {
                int m = m0 + wm * 64 + mt * 16 + lg * 4 + rr;
                Cf[(size_t)m * 512 + n] = acc[mt][nt][rr] + bz;
            }
        }
    }
}

// ---------------- Fused attention v10 (r15 structure), single-bf16 ctx out ----------------
__global__ __launch_bounds__(512, 4) void attn10(
    const __bf16* __restrict__ qh_, const __bf16* __restrict__ kh,
    const __bf16* __restrict__ vt,
    const float* __restrict__ mask, const __bf16* __restrict__ Gg,
    const float* __restrict__ rowILg,
    float* __restrict__ attn_out, __bf16* __restrict__ chi)
{
    __shared__ float nmb[1024];                        // 4 KB
    __shared__ __align__(16) __bf16 P[32][1024];       // 64 KB, swizzled
    __shared__ __align__(16) __bf16 KV[64][64];        // 8 KB chunk buffer, swizzled
    __shared__ float redl[8][16];

    const int tid = threadIdx.x;
    const int w = tid >> 6, lane = tid & 63, l15 = lane & 15, lg = lane >> 4;
    const int bid = blockIdx.x;
    const int h = bid & 7;
    const int b = (bid >> 3) & 7;
    const int q0 = (bid >> 6) * 32;
    const float L2E = 1.44269504f;
    const float c1 = 0.125f * L2E;

    char* Pb = (char*)P;
    char* KVb = (char*)KV;
    const int srow = tid >> 3;               // staging row (64 rows, 8 thr/row)
    const int scol = (tid & 7) * 8;          // staging elem offset within row
    const int sdst = srow * 128 + ((scol * 2) ^ ((srow & 7) << 4));

    #pragma unroll
    for (int i = 0; i < 2; ++i) {
        int c = tid + 512 * i;
        nmb[c] = fmaf(mask[(size_t)b * SS + c], -1e9f * L2E, -16.0f * L2E);
    }

    const size_t hb = ((size_t)(b * HH + h)) * SS * 64;
    const int qsub = w >> 2, ktw = w & 3;
    bf16x8 qf0 = *(const bf16x8*)(qh_ + hb + (size_t)(q0 + qsub * 16 + l15) * 64 + lg * 8);
    bf16x8 qf1 = *(const bf16x8*)(qh_ + hb + (size_t)(q0 + qsub * 16 + l15) * 64 + 32 + lg * 8);

    const int krow = ktw * 16 + l15;                       // K fragment row in chunk
    const int kswz = (krow & 7) << 4;
    const int prow = qsub * 16 + l15;                      // P row (q)
    const int pswz = (prow & 7) << 4;

    // ---- pass 1: 16 chunks of 64 keys, register-pipelined staging ----
    const __bf16* kcp = kh + hb + (size_t)srow * 64 + scol;
    bf16x8 kvreg = *(const bf16x8*)kcp;                    // chunk 0
    float lac = 0.f;
    for (int c = 0; c < 16; ++c) {
        __syncthreads();                                   // KV free
        *(bf16x8*)(KVb + sdst) = kvreg;                    // write chunk c
        __syncthreads();                                   // KV ready
        if (c + 1 < 16)
            kvreg = *(const bf16x8*)(kcp + (size_t)(c + 1) * 4096);  // 64 rows x 64 elems
        bf16x8 k0v = *(const bf16x8*)(KVb + krow * 128 + ((lg * 16) ^ kswz));
        bf16x8 k1v = *(const bf16x8*)(KVb + krow * 128 + ((64 + lg * 16) ^ kswz));
        f32x4 acc = {0.f, 0.f, 0.f, 0.f};
        acc = mfma16(k0v, qf0, acc);
        acc = mfma16(k1v, qf1, acc);
        const int key4 = c * 64 + ktw * 16 + lg * 4;
        f32x4 nb4 = *(const f32x4*)&nmb[key4];
        float e0 = exp2f(fmaf(acc[0], c1, nb4[0]));
        float e1 = exp2f(fmaf(acc[1], c1, nb4[1]));
        float e2 = exp2f(fmaf(acc[2], c1, nb4[2]));
        float e3 = exp2f(fmaf(acc[3], c1, nb4[3]));
        lac += (e0 + e1) + (e2 + e3);
        bf16x4 pb;
        pb[0] = (__bf16)e0; pb[1] = (__bf16)e1;
        pb[2] = (__bf16)e2; pb[3] = (__bf16)e3;
        *(bf16x4*)(Pb + prow * 2048 + ((key4 * 2) ^ pswz)) = pb;
    }
    #pragma unroll
    for (int off = 16; off <= 32; off <<= 1)
        lac += __shfl_xor(lac, off, 64);
    if (lg == 0) redl[w][l15] = lac;
    __syncthreads();

    // ---- gate phase: wave w -> q-rows [4w, 4w+4); G coalesced; fold coef ----
    const float* rg = rowILg + (size_t)b * SS + q0;
    float* aoutb = attn_out + ((size_t)(b * HH + h)) * SS * SS;
    const __bf16* gb = Gg + ((size_t)b * SS + q0) * SS;
    #pragma unroll
    for (int r = 0; r < 4; ++r) {
        const int row = w * 4 + r;
        const int rs = (row >> 4) * 4;
        const float ltot = redl[rs][row & 15] + redl[rs + 1][row & 15]
                         + redl[rs + 2][row & 15] + redl[rs + 3][row & 15];
        const float coefR = rg[row] / ltot;
        const int rswz = (row & 7) << 4;
        float* ar = aoutb + (size_t)(q0 + row) * SS;
        const __bf16* gr = gb + (size_t)row * SS;
        #pragma unroll
        for (int j = 0; j < 4; ++j) {
            const int off = lane * 8 + j * 512;            // bytes within P row
            char* pp = Pb + row * 2048 + (off ^ rswz);
            bf16x4 e4 = *(const bf16x4*)pp;
            bf16x4 g4 = *(const bf16x4*)(gr + (off >> 1));
            f32x4 av;
            bf16x4 pb;
            #pragma unroll
            for (int r2 = 0; r2 < 4; ++r2) {
                float v = (float)e4[r2] * (float)g4[r2] * coefR;
                av[r2] = v;
                pb[r2] = (__bf16)v;
            }
            __builtin_nontemporal_store(av, (f32x4*)(ar + (off >> 1)));
            *(bf16x4*)pp = pb;
        }
    }

    // ---- PV: 8 waves = 2q x 4d; V chunks register-pipelined ----
    const int dh = w & 3;
    const int vrow = dh * 16 + l15;
    const int vswz = (vrow & 7) << 4;
    f32x4 cacc = {0.f, 0.f, 0.f, 0.f};
    const __bf16* vcp = vt + ((size_t)(b * HH + h) * 64 + srow) * SS + scol;
    bf16x8 vreg = *(const bf16x8*)vcp;                     // chunk 0
    for (int c = 0; c < 16; ++c) {
        __syncthreads();                                   // KV free / P gated
        *(bf16x8*)(KVb + sdst) = vreg;
        __syncthreads();                                   // KV ready
        if (c + 1 < 16)
            vreg = *(const bf16x8*)(vcp + (c + 1) * 64);
        #pragma unroll
        for (int ks = 0; ks < 2; ++ks) {
            bf16x8 pa = *(const bf16x8*)(Pb + prow * 2048
                          + ((c * 128 + ks * 64 + lg * 16) ^ pswz));
            bf16x8 vv = *(const bf16x8*)(KVb + vrow * 128 + ((ks * 64 + lg * 16) ^ vswz));
            cacc = mfma16(pa, vv, cacc);
        }
    }

    // ---- epilogue: coef already folded; write ctx single bf16 ----
    #pragma unroll
    for (int r = 0; r < 4; ++r) {
        const int row = qsub * 16 + lg * 4 + r;
        size_t idx = ((size_t)b * SS + q0 + row) * DM + h * 64 + dh * 16 + l15;
        chi[idx] = (__bf16)cacc[r];
    }
}

extern "C" void kernel_launch(void* const* d_in, const int* in_sizes, int n_in,
                              void* d_out, int out_size, void* d_ws, size_t ws_size,
                              hipStream_t stream) {
    const float* q    = (const float*)d_in[0];
    const float* k    = (const float*)d_in[1];
    const float* v    = (const float*)d_in[2];
    const float* mask = (const float*)d_in[3];
    const float* adj  = (const float*)d_in[4];
    const float* dist = (const float*)d_in[5];
    const float* Wq   = (const float*)d_in[6];
    const float* bq   = (const float*)d_in[7];
    const float* Wk   = (const float*)d_in[8];
    const float* bk   = (const float*)d_in[9];
    const float* Wv   = (const float*)d_in[10];
    const float* bv   = (const float*)d_in[11];
    const float* Wo   = (const float*)d_in[12];
    const float* bo   = (const float*)d_in[13];

    const size_t NT = (size_t)BB * SS * DM;   // 4,194,304
    const size_t WN = 512 * 512;
    const size_t NSS = (size_t)BB * SS * SS;  // 8,388,608
    __bf16* wth = (__bf16*)d_ws;
    __bf16* wtl = wth + 4 * WN;
    __bf16* qhb = wtl + 4 * WN;
    __bf16* khb = qhb + NT;
    __bf16* vtb = khb + NT;
    __bf16* chi = vtb + NT;
    __bf16* clo = chi + NT;            // unused (kept for layout stability)
    __bf16* Gg  = clo + NT;
    float* rowILg = (float*)(Gg + NSS);

    float* outp = (float*)d_out;
    float* attn = outp + NT;

    wconv<<<dim3(8, 8, 4), 256, 0, stream>>>(Wq, Wk, Wv, Wo, wth, wtl);

    qkv_gprep<<<1408, 512, 0, stream>>>(
        q, k, v, wth, wtl, bq, bk, bv, qhb, khb, vtb,
        mask, adj, dist, Gg, rowILg);

    attn10<<<2048, 512, 0, stream>>>(qhb, khb, vtb, mask, Gg, rowILg, attn, chi);

    gemm_out3<<<dim3(4, 64), 256, 0, stream>>>(
        chi, wth, wtl, bo, outp);
}